// Round 2
// baseline (585.693 us; speedup 1.0000x reference)
//
#include <hip/hip_runtime.h>

// ILCBaseNode: T=32 steps of IF-neuron + grouped-conv feedback.
// One wave (64 lanes) per (batch, group) chain; lane o = output neuron o.
// 32768 chains = 8192 blocks x 4 waves.
//
// R1 finding: compiler sank the w[64] loads into the t-loop (VGPR_Count=40),
// re-loading all weights from L2 every step -> 283 us. Fix: pin w[] into
// VGPRs via no-op "+v" asm so rematerialization is illegal.

#define T_STEPS 32
#define BATCH 512
#define OUTD 4096           // 64 groups * 64 neurons
#define STEP_STRIDE ((size_t)BATCH * OUTD)

__global__ __launch_bounds__(256, 4)
void ilc_snn_kernel(const float* __restrict__ x_seq,
                    const float* __restrict__ conn_w,
                    const float* __restrict__ conn_b,
                    float* __restrict__ out)
{
    const int lane  = threadIdx.x & 63;
    const int wid   = threadIdx.x >> 6;
    const int chain = blockIdx.x * 4 + wid;   // 0..32767
    const int b     = chain >> 6;             // 0..511
    const int a     = chain & 63;             // 0..63

    // Lane o holds weight row w[a][o][0..63] in registers (64 VGPRs).
    float w[64];
    const float* wrow = conn_w + ((size_t)(a * 64 + lane)) * 64;
#pragma unroll
    for (int k = 0; k < 16; ++k) {
        const float4 q = *(const float4*)(wrow + 4 * k);
        w[4 * k + 0] = q.x;
        w[4 * k + 1] = q.y;
        w[4 * k + 2] = q.z;
        w[4 * k + 3] = q.w;
    }
    // Pin each weight in a VGPR: "+v" marks it modified, so the compiler
    // cannot re-load it from global inside the t-loop.
#pragma unroll
    for (int k = 0; k < 64; ++k) {
        asm volatile("" : "+v"(w[k]));
    }

    const float bias = conn_b[a * 64 + lane];

    const size_t base = (size_t)b * OUTD + (size_t)(a * 64 + lane);
    const float* xp = x_seq + base;
    float* op = out + base;

    float v = 0.0f, fb = 0.0f;
    // Prefetch depth 2: ~2 full fmac chains (~512 cyc) cover HBM latency.
    float xt0 = xp[0];
    float xt1 = xp[STEP_STRIDE];

    for (int t = 0; t < T_STEPS; ++t) {
        // Issue the t+2 prefetch before the long fmac chain (clamped index:
        // wave-uniform, always a valid address, value unused on last iters).
        const int tpf = (t + 2 < T_STEPS) ? (t + 2) : (T_STEPS - 1);
        const float xt2 = xp[(size_t)tpf * STEP_STRIDE];

        // Charge
        const float x = xt0 + fb;  // x_t + feedback (matches ref op order)
        v = v + x;
        // Fire (heaviside on v - 1.0)
        const bool  sp = (v - 1.0f) >= 0.0f;
        const float sf = sp ? 1.0f : 0.0f;
        // Hard reset
        v = sp ? 0.0f : v;
        // Emit spike
        op[(size_t)t * STEP_STRIDE] = sf;

        // Feedback matvec: fb[o] = sum_{d=0..63} s[d] * w[o][d] + bias[o]
        // Strict left-to-right order, single accumulator: bitwise-matches the
        // np reference (fmaf exact since s[d] in {0,1}) -- absmax 0.0 in R1.
        float acc = 0.0f;
        int sfi = __builtin_bit_cast(int, sf);
#pragma unroll
        for (int d = 0; d < 64; ++d) {
            const int   sdi = __builtin_amdgcn_readlane(sfi, d);
            const float sd  = __builtin_bit_cast(float, sdi);
            acc = fmaf(sd, w[d], acc);
        }
        fb = acc + bias;

        xt0 = xt1;
        xt1 = xt2;
    }
}

extern "C" void kernel_launch(void* const* d_in, const int* in_sizes, int n_in,
                              void* d_out, int out_size, void* d_ws, size_t ws_size,
                              hipStream_t stream) {
    const float* x_seq  = (const float*)d_in[0];
    const float* conn_w = (const float*)d_in[1];
    const float* conn_b = (const float*)d_in[2];
    float* out = (float*)d_out;

    dim3 grid(8192);   // 32768 chains / 4 waves per block
    dim3 block(256);
    hipLaunchKernelGGL(ilc_snn_kernel, grid, block, 0, stream,
                       x_seq, conn_w, conn_b, out);
}

// Round 4
// 585.047 us; speedup vs baseline: 1.0011x; 1.0011x over previous
//
#include <hip/hip_runtime.h>

// ILCBaseNode: T=32 steps of IF-neuron + grouped-conv feedback.
// One wave (64 lanes) per (batch, group) chain; lane o = output neuron o.
// 32768 chains = 8192 blocks x 4 waves.
//
// R1/R2 finding: `float w[64]` is a runtime-indexed alloca at SROA time ->
// never promoted to registers -> weights re-read from scratch/L1 every step
// (VGPR_Count=40, 289 us). R3's float4 "+v" asm pin doesn't compile (tied
// indirect register inputs). R4: 64 NAMED SCALAR floats (pure SSA, no
// alloca), pinned via scalar "+v" asm (16 operands per statement), matvec
// reads named scalars with constant readlane indices only.

#define T_STEPS 32
#define BATCH 512
#define OUTD 4096           // 64 groups * 64 neurons
#define STEP_STRIDE ((size_t)BATCH * OUTD)

__device__ __forceinline__ float i2f(int x) { return __builtin_bit_cast(float, x); }

// One readlane+fmac pair: strict ascending-d single-accumulator order
// (bitwise-matches np ref; fmaf exact since spike in {0,1} -- absmax 0.0
// in R1/R2).
#define STEPD(d, wreg)                                                  \
    {                                                                   \
        const int s_ = __builtin_amdgcn_readlane(sfi, d);               \
        acc = fmaf(i2f(s_), wreg, acc);                                 \
    }

__global__ __launch_bounds__(256, 4)
void ilc_snn_kernel(const float* __restrict__ x_seq,
                    const float* __restrict__ conn_w,
                    const float* __restrict__ conn_b,
                    float* __restrict__ out)
{
    const int lane  = threadIdx.x & 63;
    const int wid   = threadIdx.x >> 6;
    const int chain = blockIdx.x * 4 + wid;   // 0..32767
    const int b     = chain >> 6;             // 0..511
    const int a     = chain & 63;             // 0..63

    // Lane o's weight row w[a][o][0..63] -> 64 named scalar floats (SSA).
    const float4* wr4 = (const float4*)(conn_w + ((size_t)(a * 64 + lane)) * 64);
    float4 q;
    q = wr4[0];  float w0 = q.x,  w1 = q.y,  w2 = q.z,  w3 = q.w;
    q = wr4[1];  float w4 = q.x,  w5 = q.y,  w6 = q.z,  w7 = q.w;
    q = wr4[2];  float w8 = q.x,  w9 = q.y,  w10 = q.z, w11 = q.w;
    q = wr4[3];  float w12 = q.x, w13 = q.y, w14 = q.z, w15 = q.w;
    q = wr4[4];  float w16 = q.x, w17 = q.y, w18 = q.z, w19 = q.w;
    q = wr4[5];  float w20 = q.x, w21 = q.y, w22 = q.z, w23 = q.w;
    q = wr4[6];  float w24 = q.x, w25 = q.y, w26 = q.z, w27 = q.w;
    q = wr4[7];  float w28 = q.x, w29 = q.y, w30 = q.z, w31 = q.w;
    q = wr4[8];  float w32 = q.x, w33 = q.y, w34 = q.z, w35 = q.w;
    q = wr4[9];  float w36 = q.x, w37 = q.y, w38 = q.z, w39 = q.w;
    q = wr4[10]; float w40 = q.x, w41 = q.y, w42 = q.z, w43 = q.w;
    q = wr4[11]; float w44 = q.x, w45 = q.y, w46 = q.z, w47 = q.w;
    q = wr4[12]; float w48 = q.x, w49 = q.y, w50 = q.z, w51 = q.w;
    q = wr4[13]; float w52 = q.x, w53 = q.y, w54 = q.z, w55 = q.w;
    q = wr4[14]; float w56 = q.x, w57 = q.y, w58 = q.z, w59 = q.w;
    q = wr4[15]; float w60 = q.x, w61 = q.y, w62 = q.z, w63 = q.w;

    // Pin all 64 scalars simultaneously live in VGPRs (scalar "+v" tied
    // operands DO compile -- verified in R2). The t-loop reads only these
    // asm-defined values, so in-loop re-fetch is impossible.
    asm volatile("" : "+v"(w0),  "+v"(w1),  "+v"(w2),  "+v"(w3),
                      "+v"(w4),  "+v"(w5),  "+v"(w6),  "+v"(w7),
                      "+v"(w8),  "+v"(w9),  "+v"(w10), "+v"(w11),
                      "+v"(w12), "+v"(w13), "+v"(w14), "+v"(w15));
    asm volatile("" : "+v"(w16), "+v"(w17), "+v"(w18), "+v"(w19),
                      "+v"(w20), "+v"(w21), "+v"(w22), "+v"(w23),
                      "+v"(w24), "+v"(w25), "+v"(w26), "+v"(w27),
                      "+v"(w28), "+v"(w29), "+v"(w30), "+v"(w31));
    asm volatile("" : "+v"(w32), "+v"(w33), "+v"(w34), "+v"(w35),
                      "+v"(w36), "+v"(w37), "+v"(w38), "+v"(w39),
                      "+v"(w40), "+v"(w41), "+v"(w42), "+v"(w43),
                      "+v"(w44), "+v"(w45), "+v"(w46), "+v"(w47));
    asm volatile("" : "+v"(w48), "+v"(w49), "+v"(w50), "+v"(w51),
                      "+v"(w52), "+v"(w53), "+v"(w54), "+v"(w55),
                      "+v"(w56), "+v"(w57), "+v"(w58), "+v"(w59),
                      "+v"(w60), "+v"(w61), "+v"(w62), "+v"(w63));

    const float bias = conn_b[a * 64 + lane];

    const size_t base = (size_t)b * OUTD + (size_t)(a * 64 + lane);
    const float* xp = x_seq + base;
    float* op = out + base;

    float v = 0.0f, fb = 0.0f;
    // Prefetch depth 2: ~2 full fmac chains cover HBM latency.
    float xt0 = xp[0];
    float xt1 = xp[STEP_STRIDE];

    for (int t = 0; t < T_STEPS; ++t) {
        // Issue the t+2 prefetch before the long fmac chain (clamped index:
        // wave-uniform, always valid, value unused on last iters).
        const int tpf = (t + 2 < T_STEPS) ? (t + 2) : (T_STEPS - 1);
        const float xt2 = xp[(size_t)tpf * STEP_STRIDE];

        // Charge
        const float x = xt0 + fb;  // x_t + feedback (matches ref op order)
        v = v + x;
        // Fire (heaviside on v - 1.0)
        const bool  sp = (v - 1.0f) >= 0.0f;
        const float sf = sp ? 1.0f : 0.0f;
        // Hard reset
        v = sp ? 0.0f : v;
        // Emit spike
        op[(size_t)t * STEP_STRIDE] = sf;

        // Feedback matvec: fb[o] = sum_{d=0..63} s[d] * w[o][d] + bias[o]
        float acc = 0.0f;
        const int sfi = __builtin_bit_cast(int, sf);
        STEPD(0,  w0)  STEPD(1,  w1)  STEPD(2,  w2)  STEPD(3,  w3)
        STEPD(4,  w4)  STEPD(5,  w5)  STEPD(6,  w6)  STEPD(7,  w7)
        STEPD(8,  w8)  STEPD(9,  w9)  STEPD(10, w10) STEPD(11, w11)
        STEPD(12, w12) STEPD(13, w13) STEPD(14, w14) STEPD(15, w15)
        STEPD(16, w16) STEPD(17, w17) STEPD(18, w18) STEPD(19, w19)
        STEPD(20, w20) STEPD(21, w21) STEPD(22, w22) STEPD(23, w23)
        STEPD(24, w24) STEPD(25, w25) STEPD(26, w26) STEPD(27, w27)
        STEPD(28, w28) STEPD(29, w29) STEPD(30, w30) STEPD(31, w31)
        STEPD(32, w32) STEPD(33, w33) STEPD(34, w34) STEPD(35, w35)
        STEPD(36, w36) STEPD(37, w37) STEPD(38, w38) STEPD(39, w39)
        STEPD(40, w40) STEPD(41, w41) STEPD(42, w42) STEPD(43, w43)
        STEPD(44, w44) STEPD(45, w45) STEPD(46, w46) STEPD(47, w47)
        STEPD(48, w48) STEPD(49, w49) STEPD(50, w50) STEPD(51, w51)
        STEPD(52, w52) STEPD(53, w53) STEPD(54, w54) STEPD(55, w55)
        STEPD(56, w56) STEPD(57, w57) STEPD(58, w58) STEPD(59, w59)
        STEPD(60, w60) STEPD(61, w61) STEPD(62, w62) STEPD(63, w63)
        fb = acc + bias;

        xt0 = xt1;
        xt1 = xt2;
    }
}

extern "C" void kernel_launch(void* const* d_in, const int* in_sizes, int n_in,
                              void* d_out, int out_size, void* d_ws, size_t ws_size,
                              hipStream_t stream) {
    const float* x_seq  = (const float*)d_in[0];
    const float* conn_w = (const float*)d_in[1];
    const float* conn_b = (const float*)d_in[2];
    float* out = (float*)d_out;

    dim3 grid(8192);   // 32768 chains / 4 waves per block
    dim3 block(256);
    hipLaunchKernelGGL(ilc_snn_kernel, grid, block, 0, stream,
                       x_seq, conn_w, conn_b, out);
}